// Round 1
// baseline (810.268 us; speedup 1.0000x reference)
//
#include <hip/hip_runtime.h>
#include <math.h>

#define B 2
#define L 2048
#define D 2048
#define H 16
#define DH 128
#define M (B*L)   // 4096

typedef __attribute__((ext_vector_type(8))) short bf16x8;
typedef __attribute__((ext_vector_type(4))) float f32x4;

#define GLDS(g, l) __builtin_amdgcn_global_load_lds((const __attribute__((address_space(1))) void*)(g), \
                                                    (__attribute__((address_space(3))) void*)(l), 16, 0, 0)

__device__ __forceinline__ ushort f2bf(float f) {   // RNE f32 -> bf16
    union { float f; unsigned u; } v; v.f = f;
    unsigned r = v.u + 0x7fffu + ((v.u >> 16) & 1u);
    return (ushort)(r >> 16);
}
__device__ __forceinline__ float bf2f(ushort h) {
    union { unsigned u; float f; } v; v.u = ((unsigned)h) << 16;
    return v.f;
}
__device__ __forceinline__ unsigned pack2bf(float a, float b) {
    return (unsigned)f2bf(a) | ((unsigned)f2bf(b) << 16);
}
// truncation-pack two f32 -> bf16x2 in ONE v_perm (error <= 1ulp down, fine vs 7e-2 budget)
__device__ __forceinline__ unsigned pktrunc(float a, float b) {
    union { float f; unsigned u; } x, y; x.f = a; y.f = b;
    return __builtin_amdgcn_perm(y.u, x.u, 0x07060302);
}

// ---------------- casts ----------------
__global__ __launch_bounds__(256) void cast_f32_to_bf16(const float* __restrict__ in,
                                                        ushort* __restrict__ out) {
    const int i = blockIdx.x * 256 + threadIdx.x;
    const float4* in4 = (const float4*)in;
    float4 a = in4[2*i], b = in4[2*i+1];
    uint4 o;
    o.x = pack2bf(a.x, a.y);  o.y = pack2bf(a.z, a.w);
    o.z = pack2bf(b.x, b.y);  o.w = pack2bf(b.z, b.w);
    ((uint4*)out)[i] = o;
}

__global__ __launch_bounds__(256) void cast4_w(const float* __restrict__ w0, const float* __restrict__ w1,
                                               const float* __restrict__ w2, const float* __restrict__ w3,
                                               ushort* o0, ushort* o1, ushort* o2, ushort* o3) {
    const int z = blockIdx.y;
    const float* src = (z == 0) ? w0 : (z == 1) ? w1 : (z == 2) ? w2 : w3;
    ushort* dst = (z == 0) ? o0 : (z == 1) ? o1 : (z == 2) ? o2 : o3;
    const int i = blockIdx.x * 256 + threadIdx.x;
    const float4* in4 = (const float4*)src;
    float4 a = in4[2*i], b = in4[2*i+1];
    uint4 o;
    o.x = pack2bf(a.x, a.y);  o.y = pack2bf(a.z, a.w);
    o.z = pack2bf(b.x, b.y);  o.w = pack2bf(b.z, b.w);
    ((uint4*)dst)[i] = o;
}

// ---------------- RoPE on bf16 q,k in-place ----------------
__global__ __launch_bounds__(256) void rope_bf16(ushort* __restrict__ q, ushort* __restrict__ k,
                                                 const float* __restrict__ cosp,
                                                 const float* __restrict__ sinp) {
    const int idx = blockIdx.x * 256 + threadIdx.x;   // B*L*H*64 pairs
    const int i    = idx & 63;
    const int rest = idx >> 6;
    const int h    = rest & (H - 1);
    const int bl   = rest >> 4;
    const int l    = bl & (L - 1);
    const float c = cosp[l * 64 + i];
    const float s = sinp[l * 64 + i];
    const size_t base = (size_t)bl * D + h * DH + 2 * i;
    unsigned qv = *(unsigned*)(q + base);
    unsigned kv = *(unsigned*)(k + base);
    float q0 = bf2f((ushort)(qv & 0xffff)), q1 = bf2f((ushort)(qv >> 16));
    float k0 = bf2f((ushort)(kv & 0xffff)), k1 = bf2f((ushort)(kv >> 16));
    *(unsigned*)(q + base) = pack2bf(q0*c - q1*s, q0*s + q1*c);
    *(unsigned*)(k + base) = pack2bf(k0*c - k1*s, k0*s + k1*c);
}

// ---------------- bf16 MFMA GEMM body (NT): C[m,n] = sum_k A[m,k]*Bt[n,k] ----------------
template<bool BF16OUT>
__device__ __forceinline__ void gemm_body(const ushort* __restrict__ A,
                                          const ushort* __restrict__ Bt,
                                          void* __restrict__ Cv,
                                          int Mdim, int Ndim, int Kdim,
                                          int bx, int by) {
    __shared__ __attribute__((aligned(16))) ushort sA[4096];  // 128 x 32
    __shared__ __attribute__((aligned(16))) ushort sB[4096];
    const int tid  = threadIdx.x;
    const int lane = tid & 63, w = tid >> 6;
    const int quad = lane >> 4, l15 = lane & 15;
    const int wm = w >> 1, wn = w & 1;
    const int m0 = by * 128, n0 = bx * 128;
    const int wbase = tid & ~63;
    f32x4 acc[4][4] = {};

    for (int k0 = 0; k0 < Kdim; k0 += 32) {
#pragma unroll
        for (int i = 0; i < 2; ++i) {
            const int s = i * 256 + tid;
            const int m  = s >> 2;
            const int kc = (s & 3) ^ ((m >> 1) & 3);
            GLDS(A  + (size_t)(m0 + m) * Kdim + k0 + kc * 8, sA + (size_t)(i*256 + wbase) * 8);
            GLDS(Bt + (size_t)(n0 + m) * Kdim + k0 + kc * 8, sB + (size_t)(i*256 + wbase) * 8);
        }
        __syncthreads();
        bf16x8 af[4], bfr[4];
#pragma unroll
        for (int mt = 0; mt < 4; ++mt) {
            const int m = wm*64 + mt*16 + l15;
            const int slot = m*4 + (quad ^ ((m >> 1) & 3));
            af[mt] = *(const bf16x8*)(sA + slot*8);
        }
#pragma unroll
        for (int nt = 0; nt < 4; ++nt) {
            const int n = wn*64 + nt*16 + l15;
            const int slot = n*4 + (quad ^ ((n >> 1) & 3));
            bfr[nt] = *(const bf16x8*)(sB + slot*8);
        }
#pragma unroll
        for (int mt = 0; mt < 4; ++mt)
#pragma unroll
            for (int nt = 0; nt < 4; ++nt)
                acc[mt][nt] = __builtin_amdgcn_mfma_f32_16x16x32_bf16(af[mt], bfr[nt], acc[mt][nt], 0, 0, 0);
        __syncthreads();
    }
#pragma unroll
    for (int mt = 0; mt < 4; ++mt)
#pragma unroll
        for (int nt = 0; nt < 4; ++nt)
#pragma unroll
            for (int r = 0; r < 4; ++r) {
                const int row = m0 + wm*64 + mt*16 + quad*4 + r;
                const int col = n0 + wn*64 + nt*16 + l15;
                if (BF16OUT) ((ushort*)Cv)[(size_t)row * Ndim + col] = f2bf(acc[mt][nt][r]);
                else         ((float*) Cv)[(size_t)row * Ndim + col] = acc[mt][nt][r];
            }
}

// fused Q/K/V^T projections: z=0 Q, z=1 K, z=2 V^T (swapped block roles)
__global__ __launch_bounds__(256) void gemm_qkv(const ushort* __restrict__ xb,
                                                const ushort* __restrict__ wq,
                                                const ushort* __restrict__ wk,
                                                const ushort* __restrict__ wv,
                                                ushort* q, ushort* k, ushort* vt) {
    const int z = blockIdx.z;
    if (z == 0)      gemm_body<true>(xb, wq, q,  M, D, D, blockIdx.x, blockIdx.y);
    else if (z == 1) gemm_body<true>(xb, wk, k,  M, D, D, blockIdx.x, blockIdx.y);
    else             gemm_body<true>(wv, xb, vt, D, M, D, blockIdx.y, blockIdx.x);
}
__global__ __launch_bounds__(256) void gemm_nt_f32(const ushort* A, const ushort* Bt, float* C,
                                                   int Mdim, int Ndim, int Kdim) {
    gemm_body<false>(A, Bt, C, Mdim, Ndim, Kdim, blockIdx.x, blockIdx.y);
}

// ---------------- register-resident flash attention, key-split across 2 waves ----------------
// 128-thr block = 2 waves own the SAME 32 q-rows; wave w processes key tiles t = w, w+2, ...
// Static-max softmax (p = exp2(s*SCL-13), no running max) makes O-partials and lsum-partials
// PURE SUMS over key tiles -> the split is exactly associative; partials merged via LDS in the
// epilogue (no max-rescale combine needed). Doubles resident waves 2->4 per SIMD (VGPR=112 max)
// to cover the per-tile load->MFMA->exp2->shfl->MFMA latency chain the counters showed idle
// (MfmaUtil 9.7 / VALUBusy 16.8 / Occupancy 15.4 at 1-wave blocks).
// Block id = (63-sb)*32 + plane: all blocks of one (h,b) land on one XCD (L2 locality),
// heavy strips dispatch first.
#define SCL 0.1275174329758f   // (1/sqrt(128)) * log2(e)

__global__ __launch_bounds__(128, 4) void attn_reg(const ushort* __restrict__ qb,
                                                   const ushort* __restrict__ kb,
                                                   const ushort* __restrict__ vtb,  // V^T: [D][M]
                                                   ushort* __restrict__ ctx) {
    __shared__ __attribute__((aligned(16))) f32x4 so[2][8][64];  // wave1 O-partials, 16 KB
    __shared__ float sl[2][64];                                  // wave1 lsum-partials
    const int tid  = threadIdx.x;
    const int wave = tid >> 6;
    const int lane = tid & 63;
    const int quad = lane >> 4, l15 = lane & 15;
    const int plane = blockIdx.x & 31;
    const int h = plane & 15, b = plane >> 4;
    const int sb = 63 - (blockIdx.x >> 5);
    const int q0 = sb * 32;
    const size_t bL = (size_t)b * L;
    const int hDH = h * DH;
    const int ntiles = sb + 1;

    // ---- Q fragments (B-operand: n=q, k=dh), once; both waves load the same rows (L1/L2 hit) ----
    bf16x8 qf[2][4];
#pragma unroll
    for (int qt = 0; qt < 2; ++qt)
#pragma unroll
        for (int ks = 0; ks < 4; ++ks)
            qf[qt][ks] = *(const bf16x8*)(qb + (bL + q0 + qt*16 + l15) * D + hDH + ks*32 + quad*8);

    f32x4 o[2][8] = {};
    float lsum[2] = {0.0f, 0.0f};

    // ---- prologue: K frags for this wave's first tile (row <= bL+63, always in-bounds) ----
    bf16x8 kf[2][4];
#pragma unroll
    for (int kt2 = 0; kt2 < 2; ++kt2)
#pragma unroll
        for (int ks = 0; ks < 4; ++ks)
            kf[kt2][ks] = *(const bf16x8*)(kb + (bL + wave*32 + kt2*16 + l15) * D + hDH + ks*32 + quad*8);

    for (int t = wave; t < ntiles; t += 2) {
        const int k0 = t * 32;

        // issue V frags for this tile (consumed ~QK+softmax later)
        bf16x8 vf[8];
#pragma unroll
        for (int dt = 0; dt < 8; ++dt)
            vf[dt] = *(const bf16x8*)(vtb + (size_t)(hDH + dt*16 + l15) * M + bL + k0 + quad*8);

        // ---- S^T = K Q^T over this tile's 32 keys ----
        f32x4 st[2][2] = {};
#pragma unroll
        for (int qt = 0; qt < 2; ++qt)
#pragma unroll
            for (int kt2 = 0; kt2 < 2; ++kt2)
#pragma unroll
                for (int ks = 0; ks < 4; ++ks)
                    st[qt][kt2] = __builtin_amdgcn_mfma_f32_16x16x32_bf16(kf[kt2][ks], qf[qt][ks], st[qt][kt2], 0, 0, 0);

        // prefetch K frags for this wave's next tile (regs free after QK; ~300cyc before next use)
        if (t + 2 < ntiles) {
#pragma unroll
            for (int kt2 = 0; kt2 < 2; ++kt2)
#pragma unroll
                for (int ks = 0; ks < 4; ++ks)
                    kf[kt2][ks] = *(const bf16x8*)(kb + (bL + k0 + 64 + kt2*16 + l15) * D + hDH + ks*32 + quad*8);
        }

        // ---- static-max softmax: p = exp2(s*SCL - 13); exact after normalization ----
        const bool lastt = (t == ntiles - 1);
        unsigned pk[2][2][2];
#pragma unroll
        for (int qt = 0; qt < 2; ++qt) {
            const int q = q0 + qt*16 + l15;
            float e[2][4];
#pragma unroll
            for (int kt2 = 0; kt2 < 2; ++kt2)
#pragma unroll
                for (int r = 0; r < 4; ++r) {
                    float x = exp2f(fmaf(st[qt][kt2][r], SCL, -13.0f));
                    if (lastt && (k0 + kt2*16 + quad*4 + r > q)) x = 0.0f;
                    e[kt2][r] = x;
                    lsum[qt] += x;
                }
#pragma unroll
            for (int kt2 = 0; kt2 < 2; ++kt2) {
                pk[qt][kt2][0] = pktrunc(e[kt2][0], e[kt2][1]);
                pk[qt][kt2][1] = pktrunc(e[kt2][2], e[kt2][3]);
            }
        }

        // ---- PV: O^T += V^T P^T; B-frags gathered from pk via shuffles ----
        const int srcA = l15 + ((quad & 1) << 5);   // srcquad (quad&1)*2
        const int srcB = srcA + 16;                 // srcquad (quad&1)*2+1
        const bool hi = (quad >> 1) != 0;           // which 16-key sub-tile this lane's k covers
#pragma unroll
        for (int qt = 0; qt < 2; ++qt) {
            unsigned t00 = __shfl((int)pk[qt][0][0], srcA), t10 = __shfl((int)pk[qt][1][0], srcA);
            unsigned t01 = __shfl((int)pk[qt][0][1], srcA), t11 = __shfl((int)pk[qt][1][1], srcA);
            unsigned t02 = __shfl((int)pk[qt][0][0], srcB), t12 = __shfl((int)pk[qt][1][0], srcB);
            unsigned t03 = __shfl((int)pk[qt][0][1], srcB), t13 = __shfl((int)pk[qt][1][1], srcB);
            union { unsigned u[4]; bf16x8 v; } fr;
            fr.u[0] = hi ? t10 : t00;
            fr.u[1] = hi ? t11 : t01;
            fr.u[2] = hi ? t12 : t02;
            fr.u[3] = hi ? t13 : t03;
#pragma unroll
            for (int dt = 0; dt < 8; ++dt)
                o[qt][dt] = __builtin_amdgcn_mfma_f32_16x16x32_bf16(vf[dt], fr.v, o[qt][dt], 0, 0, 0);
        }
    }

    // ---- merge wave1 partials into wave0 via LDS (pure sums: exact) ----
    if (wave == 1) {
#pragma unroll
        for (int qt = 0; qt < 2; ++qt) {
#pragma unroll
            for (int dt = 0; dt < 8; ++dt)
                so[qt][dt][lane] = o[qt][dt];
            sl[qt][lane] = lsum[qt];
        }
    }
    __syncthreads();
    if (wave == 1) return;

#pragma unroll
    for (int qt = 0; qt < 2; ++qt) {
        lsum[qt] += sl[qt][lane];
#pragma unroll
        for (int dt = 0; dt < 8; ++dt) {
            f32x4 p = so[qt][dt][lane];
            o[qt][dt][0] += p[0]; o[qt][dt][1] += p[1];
            o[qt][dt][2] += p[2]; o[qt][dt][3] += p[3];
        }
    }

    // ---- epilogue: reduce lsum across quads, normalize, store ----
#pragma unroll
    for (int qt = 0; qt < 2; ++qt) {
        float v = lsum[qt];
        v += __shfl_xor(v, 16);
        v += __shfl_xor(v, 32);
        lsum[qt] = 1.0f / v;
    }
#pragma unroll
    for (int qt = 0; qt < 2; ++qt) {
        const size_t rowb = (bL + q0 + qt*16 + l15) * D + hDH;
        const float inv = lsum[qt];
#pragma unroll
        for (int dt = 0; dt < 8; ++dt) {
            uint2 stv;
            stv.x = pktrunc(o[qt][dt][0] * inv, o[qt][dt][1] * inv);
            stv.y = pktrunc(o[qt][dt][2] * inv, o[qt][dt][3] * inv);
            *(uint2*)(ctx + rowb + dt*16 + quad*4) = stv;
        }
    }
}

// ---------------- launch ----------------
extern "C" void kernel_launch(void* const* d_in, const int* in_sizes, int n_in,
                              void* d_out, int out_size, void* d_ws, size_t ws_size,
                              hipStream_t stream) {
    (void)in_sizes; (void)n_in; (void)out_size; (void)ws_size;
    const float* x    = (const float*)d_in[0];
    // d_in[1] = mask: causal 0/-1e9, applied analytically
    const float* cosp = (const float*)d_in[2];
    const float* sinp = (const float*)d_in[3];
    const float* wq   = (const float*)d_in[4];
    const float* wk   = (const float*)d_in[5];
    const float* wv   = (const float*)d_in[6];
    const float* wo   = (const float*)d_in[7];
    float* out = (float*)d_out;

    ushort* xb  = (ushort*)d_ws;
    ushort* wqb = xb  + (size_t)M * D;
    ushort* wkb = wqb + (size_t)D * D;
    ushort* wvb = wkb + (size_t)D * D;
    ushort* wob = wvb + (size_t)D * D;
    ushort* qb2 = wob + (size_t)D * D;
    ushort* kb2 = qb2 + (size_t)M * D;
    ushort* vtb = kb2 + (size_t)M * D;
    ushort* ctxb = xb;  // safe alias: attention only reads qb2/kb2/vtb

    cast_f32_to_bf16<<<(M*D)/2048, 256, 0, stream>>>(x, xb);
    cast4_w<<<dim3((D*D)/2048, 4), 256, 0, stream>>>(wq, wk, wv, wo, wqb, wkb, wvb, wob);

    gemm_qkv<<<dim3(16, 32, 3), 256, 0, stream>>>(xb, wqb, wkb, wvb, qb2, kb2, vtb);

    rope_bf16<<<(B*L*H*64)/256, 256, 0, stream>>>(qb2, kb2, cosp, sinp);

    attn_reg<<<dim3(64 * 32), 128, 0, stream>>>(qb2, kb2, vtb, ctxb);

    gemm_nt_f32<<<dim3(16, 32), 256, 0, stream>>>(ctxb, wob, out, M, D, D);
}

// Round 2
// 608.596 us; speedup vs baseline: 1.3314x; 1.3314x over previous
//
#include <hip/hip_runtime.h>
#include <math.h>

#define B 2
#define L 2048
#define D 2048
#define H 16
#define DH 128
#define M (B*L)   // 4096

typedef __attribute__((ext_vector_type(8))) short bf16x8;
typedef __attribute__((ext_vector_type(4))) float f32x4;

#define GLDS(g, l) __builtin_amdgcn_global_load_lds((const __attribute__((address_space(1))) void*)(g), \
                                                    (__attribute__((address_space(3))) void*)(l), 16, 0, 0)

__device__ __forceinline__ ushort f2bf(float f) {   // RNE f32 -> bf16
    union { float f; unsigned u; } v; v.f = f;
    unsigned r = v.u + 0x7fffu + ((v.u >> 16) & 1u);
    return (ushort)(r >> 16);
}
__device__ __forceinline__ float bf2f(ushort h) {
    union { unsigned u; float f; } v; v.u = ((unsigned)h) << 16;
    return v.f;
}
__device__ __forceinline__ unsigned pack2bf(float a, float b) {
    return (unsigned)f2bf(a) | ((unsigned)f2bf(b) << 16);
}
// truncation-pack two f32 -> bf16x2 in ONE v_perm (error <= 1ulp down, fine vs 7e-2 budget)
__device__ __forceinline__ unsigned pktrunc(float a, float b) {
    union { float f; unsigned u; } x, y; x.f = a; y.f = b;
    return __builtin_amdgcn_perm(y.u, x.u, 0x07060302);
}

// ---------------- casts ----------------
__global__ __launch_bounds__(256) void cast_f32_to_bf16(const float* __restrict__ in,
                                                        ushort* __restrict__ out) {
    const int i = blockIdx.x * 256 + threadIdx.x;
    const float4* in4 = (const float4*)in;
    float4 a = in4[2*i], b = in4[2*i+1];
    uint4 o;
    o.x = pack2bf(a.x, a.y);  o.y = pack2bf(a.z, a.w);
    o.z = pack2bf(b.x, b.y);  o.w = pack2bf(b.z, b.w);
    ((uint4*)out)[i] = o;
}

__global__ __launch_bounds__(256) void cast4_w(const float* __restrict__ w0, const float* __restrict__ w1,
                                               const float* __restrict__ w2, const float* __restrict__ w3,
                                               ushort* o0, ushort* o1, ushort* o2, ushort* o3) {
    const int z = blockIdx.y;
    const float* src = (z == 0) ? w0 : (z == 1) ? w1 : (z == 2) ? w2 : w3;
    ushort* dst = (z == 0) ? o0 : (z == 1) ? o1 : (z == 2) ? o2 : o3;
    const int i = blockIdx.x * 256 + threadIdx.x;
    const float4* in4 = (const float4*)src;
    float4 a = in4[2*i], b = in4[2*i+1];
    uint4 o;
    o.x = pack2bf(a.x, a.y);  o.y = pack2bf(a.z, a.w);
    o.z = pack2bf(b.x, b.y);  o.w = pack2bf(b.z, b.w);
    ((uint4*)dst)[i] = o;
}

// ---------------- RoPE on bf16 q,k in-place ----------------
__global__ __launch_bounds__(256) void rope_bf16(ushort* __restrict__ q, ushort* __restrict__ k,
                                                 const float* __restrict__ cosp,
                                                 const float* __restrict__ sinp) {
    const int idx = blockIdx.x * 256 + threadIdx.x;   // B*L*H*64 pairs
    const int i    = idx & 63;
    const int rest = idx >> 6;
    const int h    = rest & (H - 1);
    const int bl   = rest >> 4;
    const int l    = bl & (L - 1);
    const float c = cosp[l * 64 + i];
    const float s = sinp[l * 64 + i];
    const size_t base = (size_t)bl * D + h * DH + 2 * i;
    unsigned qv = *(unsigned*)(q + base);
    unsigned kv = *(unsigned*)(k + base);
    float q0 = bf2f((ushort)(qv & 0xffff)), q1 = bf2f((ushort)(qv >> 16));
    float k0 = bf2f((ushort)(kv & 0xffff)), k1 = bf2f((ushort)(kv >> 16));
    *(unsigned*)(q + base) = pack2bf(q0*c - q1*s, q0*s + q1*c);
    *(unsigned*)(k + base) = pack2bf(k0*c - k1*s, k0*s + k1*c);
}

// ---------------- bf16 MFMA GEMM body (NT): C[m,n] = sum_k A[m,k]*Bt[n,k] ----------------
template<bool BF16OUT>
__device__ __forceinline__ void gemm_body(const ushort* __restrict__ A,
                                          const ushort* __restrict__ Bt,
                                          void* __restrict__ Cv,
                                          int Mdim, int Ndim, int Kdim,
                                          int bx, int by) {
    __shared__ __attribute__((aligned(16))) ushort sA[4096];  // 128 x 32
    __shared__ __attribute__((aligned(16))) ushort sB[4096];
    const int tid  = threadIdx.x;
    const int lane = tid & 63, w = tid >> 6;
    const int quad = lane >> 4, l15 = lane & 15;
    const int wm = w >> 1, wn = w & 1;
    const int m0 = by * 128, n0 = bx * 128;
    const int wbase = tid & ~63;
    f32x4 acc[4][4] = {};

    for (int k0 = 0; k0 < Kdim; k0 += 32) {
#pragma unroll
        for (int i = 0; i < 2; ++i) {
            const int s = i * 256 + tid;
            const int m  = s >> 2;
            const int kc = (s & 3) ^ ((m >> 1) & 3);
            GLDS(A  + (size_t)(m0 + m) * Kdim + k0 + kc * 8, sA + (size_t)(i*256 + wbase) * 8);
            GLDS(Bt + (size_t)(n0 + m) * Kdim + k0 + kc * 8, sB + (size_t)(i*256 + wbase) * 8);
        }
        __syncthreads();
        bf16x8 af[4], bfr[4];
#pragma unroll
        for (int mt = 0; mt < 4; ++mt) {
            const int m = wm*64 + mt*16 + l15;
            const int slot = m*4 + (quad ^ ((m >> 1) & 3));
            af[mt] = *(const bf16x8*)(sA + slot*8);
        }
#pragma unroll
        for (int nt = 0; nt < 4; ++nt) {
            const int n = wn*64 + nt*16 + l15;
            const int slot = n*4 + (quad ^ ((n >> 1) & 3));
            bfr[nt] = *(const bf16x8*)(sB + slot*8);
        }
#pragma unroll
        for (int mt = 0; mt < 4; ++mt)
#pragma unroll
            for (int nt = 0; nt < 4; ++nt)
                acc[mt][nt] = __builtin_amdgcn_mfma_f32_16x16x32_bf16(af[mt], bfr[nt], acc[mt][nt], 0, 0, 0);
        __syncthreads();
    }
#pragma unroll
    for (int mt = 0; mt < 4; ++mt)
#pragma unroll
        for (int nt = 0; nt < 4; ++nt)
#pragma unroll
            for (int r = 0; r < 4; ++r) {
                const int row = m0 + wm*64 + mt*16 + quad*4 + r;
                const int col = n0 + wn*64 + nt*16 + l15;
                if (BF16OUT) ((ushort*)Cv)[(size_t)row * Ndim + col] = f2bf(acc[mt][nt][r]);
                else         ((float*) Cv)[(size_t)row * Ndim + col] = acc[mt][nt][r];
            }
}

// fused Q/K/V^T projections: z=0 Q, z=1 K, z=2 V^T (swapped block roles)
__global__ __launch_bounds__(256) void gemm_qkv(const ushort* __restrict__ xb,
                                                const ushort* __restrict__ wq,
                                                const ushort* __restrict__ wk,
                                                const ushort* __restrict__ wv,
                                                ushort* q, ushort* k, ushort* vt) {
    const int z = blockIdx.z;
    if (z == 0)      gemm_body<true>(xb, wq, q,  M, D, D, blockIdx.x, blockIdx.y);
    else if (z == 1) gemm_body<true>(xb, wk, k,  M, D, D, blockIdx.x, blockIdx.y);
    else             gemm_body<true>(wv, xb, vt, D, M, D, blockIdx.y, blockIdx.x);
}
__global__ __launch_bounds__(256) void gemm_nt_f32(const ushort* A, const ushort* Bt, float* C,
                                                   int Mdim, int Ndim, int Kdim) {
    gemm_body<false>(A, Bt, C, Mdim, Ndim, Kdim, blockIdx.x, blockIdx.y);
}

// ---------------- register-resident flash attention, 16 q-rows per wave ----------------
// One wave (64-thr block) owns 16 q-rows (was 32): halves per-wave register state
// (o[8] instead of o[2][8], qf[4] instead of qf[2][4]) so VGPR fits well under the
// __launch_bounds__(64,4) 128-cap WITHOUT spilling (round-1 lesson: forcing waves
// below natural allocation = 2 GB scratch traffic), and doubles the grid to 4096
// single-wave blocks = 4 waves/SIMD (was grid-capped at 2). Total MFMA/exp2 work
// unchanged; K/V reads double but are L2-resident per (b,h) via the XCD swizzle.
// Block id = (127-sb)*32 + plane: all strips of one (h,b) land on one XCD,
// heavy strips dispatch first.
#define SCL 0.1275174329758f   // (1/sqrt(128)) * log2(e)

__global__ __launch_bounds__(64, 4) void attn_reg(const ushort* __restrict__ qb,
                                                  const ushort* __restrict__ kb,
                                                  const ushort* __restrict__ vtb,  // V^T: [D][M]
                                                  ushort* __restrict__ ctx) {
    const int lane = threadIdx.x & 63;
    const int quad = lane >> 4, l15 = lane & 15;
    const int plane = blockIdx.x & 31;
    const int h = plane & 15, b = plane >> 4;
    const int sb = 127 - (blockIdx.x >> 5);
    const int q0 = sb * 16;
    const size_t bL = (size_t)b * L;
    const int hDH = h * DH;
    const int ntiles = (sb + 2) >> 1;   // keys 0..q0+15 in 32-wide tiles

    // ---- Q fragments (B-operand: n=q, k=dh), once ----
    bf16x8 qf[4];
#pragma unroll
    for (int ks = 0; ks < 4; ++ks)
        qf[ks] = *(const bf16x8*)(qb + (bL + q0 + l15) * D + hDH + ks*32 + quad*8);

    f32x4 o[8] = {};
    float lsum = 0.0f;

    // ---- prologue: K frags for tile 0 ----
    bf16x8 kf[2][4];
#pragma unroll
    for (int kt2 = 0; kt2 < 2; ++kt2)
#pragma unroll
        for (int ks = 0; ks < 4; ++ks)
            kf[kt2][ks] = *(const bf16x8*)(kb + (bL + kt2*16 + l15) * D + hDH + ks*32 + quad*8);

    for (int t = 0; t < ntiles; ++t) {
        const int k0 = t * 32;

        // issue V frags for this tile (consumed ~QK+softmax later)
        bf16x8 vf[8];
#pragma unroll
        for (int dt = 0; dt < 8; ++dt)
            vf[dt] = *(const bf16x8*)(vtb + (size_t)(hDH + dt*16 + l15) * M + bL + k0 + quad*8);

        // ---- S^T = K Q^T over this tile's 32 keys (16 q cols) ----
        f32x4 st[2] = {};
#pragma unroll
        for (int kt2 = 0; kt2 < 2; ++kt2)
#pragma unroll
            for (int ks = 0; ks < 4; ++ks)
                st[kt2] = __builtin_amdgcn_mfma_f32_16x16x32_bf16(kf[kt2][ks], qf[ks], st[kt2], 0, 0, 0);

        // prefetch K frags for tile t+1 (regs free after QK; ~300cyc before next use)
        if (t + 1 < ntiles) {
#pragma unroll
            for (int kt2 = 0; kt2 < 2; ++kt2)
#pragma unroll
                for (int ks = 0; ks < 4; ++ks)
                    kf[kt2][ks] = *(const bf16x8*)(kb + (bL + k0 + 32 + kt2*16 + l15) * D + hDH + ks*32 + quad*8);
        }

        // ---- static-max softmax: p = exp2(s*SCL - 13); exact after normalization ----
        const bool lastt = (t == ntiles - 1);
        const int q = q0 + l15;
        unsigned pk[2][2];
        {
            float e[2][4];
#pragma unroll
            for (int kt2 = 0; kt2 < 2; ++kt2)
#pragma unroll
                for (int r = 0; r < 4; ++r) {
                    float x = exp2f(fmaf(st[kt2][r], SCL, -13.0f));
                    if (lastt && (k0 + kt2*16 + quad*4 + r > q)) x = 0.0f;
                    e[kt2][r] = x;
                    lsum += x;
                }
#pragma unroll
            for (int kt2 = 0; kt2 < 2; ++kt2) {
                pk[kt2][0] = pktrunc(e[kt2][0], e[kt2][1]);
                pk[kt2][1] = pktrunc(e[kt2][2], e[kt2][3]);
            }
        }

        // ---- PV: O^T += V^T P^T; B-frags gathered from pk via shuffles ----
        const int srcA = l15 + ((quad & 1) << 5);   // srcquad (quad&1)*2
        const int srcB = srcA + 16;                 // srcquad (quad&1)*2+1
        const bool hi = (quad >> 1) != 0;           // which 16-key sub-tile this lane's k covers
        {
            unsigned t00 = __shfl((int)pk[0][0], srcA), t10 = __shfl((int)pk[1][0], srcA);
            unsigned t01 = __shfl((int)pk[0][1], srcA), t11 = __shfl((int)pk[1][1], srcA);
            unsigned t02 = __shfl((int)pk[0][0], srcB), t12 = __shfl((int)pk[1][0], srcB);
            unsigned t03 = __shfl((int)pk[0][1], srcB), t13 = __shfl((int)pk[1][1], srcB);
            union { unsigned u[4]; bf16x8 v; } fr;
            fr.u[0] = hi ? t10 : t00;
            fr.u[1] = hi ? t11 : t01;
            fr.u[2] = hi ? t12 : t02;
            fr.u[3] = hi ? t13 : t03;
#pragma unroll
            for (int dt = 0; dt < 8; ++dt)
                o[dt] = __builtin_amdgcn_mfma_f32_16x16x32_bf16(vf[dt], fr.v, o[dt], 0, 0, 0);
        }
    }

    // ---- epilogue: reduce lsum across quads, normalize, store ----
    {
        float v = lsum;
        v += __shfl_xor(v, 16);
        v += __shfl_xor(v, 32);
        lsum = 1.0f / v;
    }
    {
        const size_t rowb = (bL + q0 + l15) * D + hDH;
        const float inv = lsum;
#pragma unroll
        for (int dt = 0; dt < 8; ++dt) {
            uint2 stv;
            stv.x = pktrunc(o[dt][0] * inv, o[dt][1] * inv);
            stv.y = pktrunc(o[dt][2] * inv, o[dt][3] * inv);
            *(uint2*)(ctx + rowb + dt*16 + quad*4) = stv;
        }
    }
}

// ---------------- launch ----------------
extern "C" void kernel_launch(void* const* d_in, const int* in_sizes, int n_in,
                              void* d_out, int out_size, void* d_ws, size_t ws_size,
                              hipStream_t stream) {
    (void)in_sizes; (void)n_in; (void)out_size; (void)ws_size;
    const float* x    = (const float*)d_in[0];
    // d_in[1] = mask: causal 0/-1e9, applied analytically
    const float* cosp = (const float*)d_in[2];
    const float* sinp = (const float*)d_in[3];
    const float* wq   = (const float*)d_in[4];
    const float* wk   = (const float*)d_in[5];
    const float* wv   = (const float*)d_in[6];
    const float* wo   = (const float*)d_in[7];
    float* out = (float*)d_out;

    ushort* xb  = (ushort*)d_ws;
    ushort* wqb = xb  + (size_t)M * D;
    ushort* wkb = wqb + (size_t)D * D;
    ushort* wvb = wkb + (size_t)D * D;
    ushort* wob = wvb + (size_t)D * D;
    ushort* qb2 = wob + (size_t)D * D;
    ushort* kb2 = qb2 + (size_t)M * D;
    ushort* vtb = kb2 + (size_t)M * D;
    ushort* ctxb = xb;  // safe alias: attention only reads qb2/kb2/vtb

    cast_f32_to_bf16<<<(M*D)/2048, 256, 0, stream>>>(x, xb);
    cast4_w<<<dim3((D*D)/2048, 4), 256, 0, stream>>>(wq, wk, wv, wo, wqb, wkb, wvb, wob);

    gemm_qkv<<<dim3(16, 32, 3), 256, 0, stream>>>(xb, wqb, wkb, wvb, qb2, kb2, vtb);

    rope_bf16<<<(B*L*H*64)/256, 256, 0, stream>>>(qb2, kb2, cosp, sinp);

    attn_reg<<<dim3(128 * 32), 64, 0, stream>>>(qb2, kb2, vtb, ctxb);

    gemm_nt_f32<<<dim3(16, 32), 256, 0, stream>>>(ctxb, wob, out, M, D, D);
}

// Round 3
// 422.118 us; speedup vs baseline: 1.9195x; 1.4418x over previous
//
#include <hip/hip_runtime.h>
#include <math.h>

#define B 2
#define L 2048
#define D 2048
#define H 16
#define DH 128
#define M (B*L)   // 4096

typedef __attribute__((ext_vector_type(8))) short bf16x8;
typedef __attribute__((ext_vector_type(4))) float f32x4;

#define GLDS(g, l) __builtin_amdgcn_global_load_lds((const __attribute__((address_space(1))) void*)(g), \
                                                    (__attribute__((address_space(3))) void*)(l), 16, 0, 0)

__device__ __forceinline__ ushort f2bf(float f) {   // RNE f32 -> bf16
    union { float f; unsigned u; } v; v.f = f;
    unsigned r = v.u + 0x7fffu + ((v.u >> 16) & 1u);
    return (ushort)(r >> 16);
}
__device__ __forceinline__ float bf2f(ushort h) {
    union { unsigned u; float f; } v; v.u = ((unsigned)h) << 16;
    return v.f;
}
__device__ __forceinline__ unsigned pack2bf(float a, float b) {
    return (unsigned)f2bf(a) | ((unsigned)f2bf(b) << 16);
}
// truncation-pack two f32 -> bf16x2 in ONE v_perm (error <= 1ulp down, fine vs 7e-2 budget)
__device__ __forceinline__ unsigned pktrunc(float a, float b) {
    union { float f; unsigned u; } x, y; x.f = a; y.f = b;
    return __builtin_amdgcn_perm(y.u, x.u, 0x07060302);
}

// ---------------- casts ----------------
__global__ __launch_bounds__(256) void cast_f32_to_bf16(const float* __restrict__ in,
                                                        ushort* __restrict__ out) {
    const int i = blockIdx.x * 256 + threadIdx.x;
    const float4* in4 = (const float4*)in;
    float4 a = in4[2*i], b = in4[2*i+1];
    uint4 o;
    o.x = pack2bf(a.x, a.y);  o.y = pack2bf(a.z, a.w);
    o.z = pack2bf(b.x, b.y);  o.w = pack2bf(b.z, b.w);
    ((uint4*)out)[i] = o;
}

__global__ __launch_bounds__(256) void cast4_w(const float* __restrict__ w0, const float* __restrict__ w1,
                                               const float* __restrict__ w2, const float* __restrict__ w3,
                                               ushort* o0, ushort* o1, ushort* o2, ushort* o3) {
    const int z = blockIdx.y;
    const float* src = (z == 0) ? w0 : (z == 1) ? w1 : (z == 2) ? w2 : w3;
    ushort* dst = (z == 0) ? o0 : (z == 1) ? o1 : (z == 2) ? o2 : o3;
    const int i = blockIdx.x * 256 + threadIdx.x;
    const float4* in4 = (const float4*)src;
    float4 a = in4[2*i], b = in4[2*i+1];
    uint4 o;
    o.x = pack2bf(a.x, a.y);  o.y = pack2bf(a.z, a.w);
    o.z = pack2bf(b.x, b.y);  o.w = pack2bf(b.z, b.w);
    ((uint4*)dst)[i] = o;
}

// ---------------- RoPE on bf16 q,k in-place ----------------
__global__ __launch_bounds__(256) void rope_bf16(ushort* __restrict__ q, ushort* __restrict__ k,
                                                 const float* __restrict__ cosp,
                                                 const float* __restrict__ sinp) {
    const int idx = blockIdx.x * 256 + threadIdx.x;   // B*L*H*64 pairs
    const int i    = idx & 63;
    const int rest = idx >> 6;
    const int h    = rest & (H - 1);
    const int bl   = rest >> 4;
    const int l    = bl & (L - 1);
    const float c = cosp[l * 64 + i];
    const float s = sinp[l * 64 + i];
    const size_t base = (size_t)bl * D + h * DH + 2 * i;
    unsigned qv = *(unsigned*)(q + base);
    unsigned kv = *(unsigned*)(k + base);
    float q0 = bf2f((ushort)(qv & 0xffff)), q1 = bf2f((ushort)(qv >> 16));
    float k0 = bf2f((ushort)(kv & 0xffff)), k1 = bf2f((ushort)(kv >> 16));
    *(unsigned*)(q + base) = pack2bf(q0*c - q1*s, q0*s + q1*c);
    *(unsigned*)(k + base) = pack2bf(k0*c - k1*s, k0*s + k1*c);
}

// ---------------- bf16 MFMA GEMM body (NT): C[m,n] = sum_k A[m,k]*Bt[n,k] ----------------
template<bool BF16OUT>
__device__ __forceinline__ void gemm_body(const ushort* __restrict__ A,
                                          const ushort* __restrict__ Bt,
                                          void* __restrict__ Cv,
                                          int Mdim, int Ndim, int Kdim,
                                          int bx, int by) {
    __shared__ __attribute__((aligned(16))) ushort sA[4096];  // 128 x 32
    __shared__ __attribute__((aligned(16))) ushort sB[4096];
    const int tid  = threadIdx.x;
    const int lane = tid & 63, w = tid >> 6;
    const int quad = lane >> 4, l15 = lane & 15;
    const int wm = w >> 1, wn = w & 1;
    const int m0 = by * 128, n0 = bx * 128;
    const int wbase = tid & ~63;
    f32x4 acc[4][4] = {};

    for (int k0 = 0; k0 < Kdim; k0 += 32) {
#pragma unroll
        for (int i = 0; i < 2; ++i) {
            const int s = i * 256 + tid;
            const int m  = s >> 2;
            const int kc = (s & 3) ^ ((m >> 1) & 3);
            GLDS(A  + (size_t)(m0 + m) * Kdim + k0 + kc * 8, sA + (size_t)(i*256 + wbase) * 8);
            GLDS(Bt + (size_t)(n0 + m) * Kdim + k0 + kc * 8, sB + (size_t)(i*256 + wbase) * 8);
        }
        __syncthreads();
        bf16x8 af[4], bfr[4];
#pragma unroll
        for (int mt = 0; mt < 4; ++mt) {
            const int m = wm*64 + mt*16 + l15;
            const int slot = m*4 + (quad ^ ((m >> 1) & 3));
            af[mt] = *(const bf16x8*)(sA + slot*8);
        }
#pragma unroll
        for (int nt = 0; nt < 4; ++nt) {
            const int n = wn*64 + nt*16 + l15;
            const int slot = n*4 + (quad ^ ((n >> 1) & 3));
            bfr[nt] = *(const bf16x8*)(sB + slot*8);
        }
#pragma unroll
        for (int mt = 0; mt < 4; ++mt)
#pragma unroll
            for (int nt = 0; nt < 4; ++nt)
                acc[mt][nt] = __builtin_amdgcn_mfma_f32_16x16x32_bf16(af[mt], bfr[nt], acc[mt][nt], 0, 0, 0);
        __syncthreads();
    }
#pragma unroll
    for (int mt = 0; mt < 4; ++mt)
#pragma unroll
        for (int nt = 0; nt < 4; ++nt)
#pragma unroll
            for (int r = 0; r < 4; ++r) {
                const int row = m0 + wm*64 + mt*16 + quad*4 + r;
                const int col = n0 + wn*64 + nt*16 + l15;
                if (BF16OUT) ((ushort*)Cv)[(size_t)row * Ndim + col] = f2bf(acc[mt][nt][r]);
                else         ((float*) Cv)[(size_t)row * Ndim + col] = acc[mt][nt][r];
            }
}

// fused Q/K/V^T projections: z=0 Q, z=1 K, z=2 V^T (swapped block roles)
__global__ __launch_bounds__(256) void gemm_qkv(const ushort* __restrict__ xb,
                                                const ushort* __restrict__ wq,
                                                const ushort* __restrict__ wk,
                                                const ushort* __restrict__ wv,
                                                ushort* q, ushort* k, ushort* vt) {
    const int z = blockIdx.z;
    if (z == 0)      gemm_body<true>(xb, wq, q,  M, D, D, blockIdx.x, blockIdx.y);
    else if (z == 1) gemm_body<true>(xb, wk, k,  M, D, D, blockIdx.x, blockIdx.y);
    else             gemm_body<true>(wv, xb, vt, D, M, D, blockIdx.y, blockIdx.x);
}
__global__ __launch_bounds__(256) void gemm_nt_f32(const ushort* A, const ushort* Bt, float* C,
                                                   int Mdim, int Ndim, int Kdim) {
    gemm_body<false>(A, Bt, C, Mdim, Ndim, Kdim, blockIdx.x, blockIdx.y);
}

// ---------------- LDS-staged flash attention: 4 waves x 16 q-rows, double-buffered K/V ----------------
// Rounds 0-2 showed the reg-resident kernel is GLOBAL-LATENCY bound and that bytes-in-flight
// per wave (held in VGPRs) is the binding resource: more waves with fewer regs = slower.
// Fix: decouple bytes-in-flight from VGPRs via global_load_lds double-buffered staging.
// Block = 256 thr = 4 waves sharing one 64-row q-strip; per 32-key tile the block stages
// K(32x128) + V^T(128x32) = 16KB with 4 DMA/thread (zero VGPR), prefetching tile t+1
// during compute of tile t. One __syncthreads per tile (implicit vmcnt(0)+lgkmcnt(0) drain
// makes the buffer swap race-free). K/V L2 traffic = half of round 0, quarter of round 2.
// Swizzle per rule #21: linear LDS dest, XOR-swizzled GLOBAL source, same XOR on ds_read:
//   K  slot(key,phys):  phys = chunk_log ^ (key&7)      (chunk = 8 dh elems, 16/row)
//   V^T slot(row,phys): phys = chunk_log ^ ((row>>1)&3) (chunk = 8 keys, 4/row; gemm_body's proven pattern)
// Both read patterns hit the 8-access/bank minimum (conflict-free).
#define SCL 0.1275174329758f   // (1/sqrt(128)) * log2(e)

__global__ __launch_bounds__(256) void attn_lds(const ushort* __restrict__ qb,
                                                const ushort* __restrict__ kb,
                                                const ushort* __restrict__ vtb,  // V^T: [D][M]
                                                ushort* __restrict__ ctx) {
    __shared__ __attribute__((aligned(16))) ushort sK[2][32*128];   // 2 x 8KB
    __shared__ __attribute__((aligned(16))) ushort sV[2][128*32];   // 2 x 8KB
    const int tid  = threadIdx.x;
    const int w    = tid >> 6;
    const int lane = tid & 63;
    const int quad = lane >> 4, l15 = lane & 15;
    const int wbase = tid & ~63;
    const int plane = blockIdx.x & 31;
    const int h = plane & 15, b = plane >> 4;
    const int sb = 31 - (blockIdx.x >> 5);    // heavy strips dispatch first
    const int q0 = sb * 64;
    const size_t bL = (size_t)b * L;
    const int hDH = h * DH;
    const int ntiles = 2 * (sb + 1);          // 32-key tiles covering keys 0..q0+63
    const int tmask  = sb * 2 + (w >> 1);     // first tile needing causal mask for this wave
    const int qrow   = q0 + w * 16 + l15;     // this lane's q column in S^T

    // ---- Q fragments (B-operand: n=q, k=dh), once ----
    bf16x8 qf[4];
#pragma unroll
    for (int ks = 0; ks < 4; ++ks)
        qf[ks] = *(const bf16x8*)(qb + (bL + qrow) * D + hDH + ks*32 + quad*8);

    f32x4 o[8] = {};
    float lsum = 0.0f;

    // ---- stage tile t into LDS buffer buf: K 512 slots + V 512 slots of 16B ----
    #define STAGE(buf, t) do {                                                              \
        const int k0s = (t) * 32;                                                           \
        _Pragma("unroll")                                                                   \
        for (int j = 0; j < 2; ++j) {                                                       \
            const int s = j*256 + tid;                                                      \
            const int key = s >> 4, phys = s & 15;                                          \
            const int logc = phys ^ (key & 7);                                              \
            GLDS(kb + (bL + k0s + key) * (size_t)D + hDH + logc*8,                          \
                 sK[buf] + (size_t)(j*256 + wbase) * 8);                                    \
        }                                                                                   \
        _Pragma("unroll")                                                                   \
        for (int j = 0; j < 2; ++j) {                                                       \
            const int s = j*256 + tid;                                                      \
            const int row = s >> 2, physc = s & 3;                                          \
            const int logc = physc ^ ((row >> 1) & 3);                                      \
            GLDS(vtb + (size_t)(hDH + row) * M + bL + k0s + logc*8,                         \
                 sV[buf] + (size_t)(j*256 + wbase) * 8);                                    \
        }                                                                                   \
    } while (0)

    int cur = 0;
    STAGE(0, 0);
    __syncthreads();

    for (int t = 0; t < ntiles; ++t) {
        if (t + 1 < ntiles) STAGE(cur ^ 1, t + 1);   // prefetch next tile into other buffer
        const ushort* sKc = sK[cur];
        const ushort* sVc = sV[cur];
        const int k0 = t * 32;

        // ---- S^T = K Q^T over this tile's 32 keys (16 q cols per wave) ----
        f32x4 st[2] = {};
#pragma unroll
        for (int kt2 = 0; kt2 < 2; ++kt2)
#pragma unroll
            for (int ks = 0; ks < 4; ++ks) {
                bf16x8 kfr = *(const bf16x8*)(sKc + ((kt2*16 + l15)*16 + ((ks*4 + quad) ^ (l15 & 7)))*8);
                st[kt2] = __builtin_amdgcn_mfma_f32_16x16x32_bf16(kfr, qf[ks], st[kt2], 0, 0, 0);
            }

        // ---- static-max softmax: p = exp2(s*SCL - 13); exact after normalization ----
        const bool domask = (t >= tmask);
        unsigned pk[2][2];
        {
            float e[2][4];
#pragma unroll
            for (int kt2 = 0; kt2 < 2; ++kt2)
#pragma unroll
                for (int r = 0; r < 4; ++r) {
                    float x = exp2f(fmaf(st[kt2][r], SCL, -13.0f));
                    if (domask && (k0 + kt2*16 + quad*4 + r > qrow)) x = 0.0f;
                    e[kt2][r] = x;
                    lsum += x;
                }
#pragma unroll
            for (int kt2 = 0; kt2 < 2; ++kt2) {
                pk[kt2][0] = pktrunc(e[kt2][0], e[kt2][1]);
                pk[kt2][1] = pktrunc(e[kt2][2], e[kt2][3]);
            }
        }

        // ---- PV: O^T += V^T P^T; B-frags gathered from pk via shuffles ----
        const int srcA = l15 + ((quad & 1) << 5);   // srcquad (quad&1)*2
        const int srcB = srcA + 16;                 // srcquad (quad&1)*2+1
        const bool hi = (quad >> 1) != 0;           // which 16-key sub-tile this lane's k covers
        {
            unsigned t00 = __shfl((int)pk[0][0], srcA), t10 = __shfl((int)pk[1][0], srcA);
            unsigned t01 = __shfl((int)pk[0][1], srcA), t11 = __shfl((int)pk[1][1], srcA);
            unsigned t02 = __shfl((int)pk[0][0], srcB), t12 = __shfl((int)pk[1][0], srcB);
            unsigned t03 = __shfl((int)pk[0][1], srcB), t13 = __shfl((int)pk[1][1], srcB);
            union { unsigned u[4]; bf16x8 v; } fr;
            fr.u[0] = hi ? t10 : t00;
            fr.u[1] = hi ? t11 : t01;
            fr.u[2] = hi ? t12 : t02;
            fr.u[3] = hi ? t13 : t13*0 + (hi ? t13 : t03);
            fr.u[3] = hi ? t13 : t03;
#pragma unroll
            for (int dt = 0; dt < 8; ++dt) {
                bf16x8 vfr = *(const bf16x8*)(sVc + ((dt*16 + l15)*4 + (quad ^ ((l15 >> 1) & 3)))*8);
                o[dt] = __builtin_amdgcn_mfma_f32_16x16x32_bf16(vfr, fr.v, o[dt], 0, 0, 0);
            }
        }

        __syncthreads();   // stage(t+1) complete + all waves done reading buf[cur]
        cur ^= 1;
    }

    // ---- epilogue: reduce lsum across quads, normalize, store ----
    {
        float v = lsum;
        v += __shfl_xor(v, 16);
        v += __shfl_xor(v, 32);
        lsum = 1.0f / v;
    }
    {
        const size_t rowb = (bL + qrow) * D + hDH;
        const float inv = lsum;
#pragma unroll
        for (int dt = 0; dt < 8; ++dt) {
            uint2 stv;
            stv.x = pktrunc(o[dt][0] * inv, o[dt][1] * inv);
            stv.y = pktrunc(o[dt][2] * inv, o[dt][3] * inv);
            *(uint2*)(ctx + rowb + dt*16 + quad*4) = stv;
        }
    }
    #undef STAGE
}

// ---------------- launch ----------------
extern "C" void kernel_launch(void* const* d_in, const int* in_sizes, int n_in,
                              void* d_out, int out_size, void* d_ws, size_t ws_size,
                              hipStream_t stream) {
    (void)in_sizes; (void)n_in; (void)out_size; (void)ws_size;
    const float* x    = (const float*)d_in[0];
    // d_in[1] = mask: causal 0/-1e9, applied analytically
    const float* cosp = (const float*)d_in[2];
    const float* sinp = (const float*)d_in[3];
    const float* wq   = (const float*)d_in[4];
    const float* wk   = (const float*)d_in[5];
    const float* wv   = (const float*)d_in[6];
    const float* wo   = (const float*)d_in[7];
    float* out = (float*)d_out;

    ushort* xb  = (ushort*)d_ws;
    ushort* wqb = xb  + (size_t)M * D;
    ushort* wkb = wqb + (size_t)D * D;
    ushort* wvb = wkb + (size_t)D * D;
    ushort* wob = wvb + (size_t)D * D;
    ushort* qb2 = wob + (size_t)D * D;
    ushort* kb2 = qb2 + (size_t)M * D;
    ushort* vtb = kb2 + (size_t)M * D;
    ushort* ctxb = xb;  // safe alias: attention only reads qb2/kb2/vtb

    cast_f32_to_bf16<<<(M*D)/2048, 256, 0, stream>>>(x, xb);
    cast4_w<<<dim3((D*D)/2048, 4), 256, 0, stream>>>(wq, wk, wv, wo, wqb, wkb, wvb, wob);

    gemm_qkv<<<dim3(16, 32, 3), 256, 0, stream>>>(xb, wqb, wkb, wvb, qb2, kb2, vtb);

    rope_bf16<<<(B*L*H*64)/256, 256, 0, stream>>>(qb2, kb2, cosp, sinp);

    attn_lds<<<dim3(32 * 32), 256, 0, stream>>>(qb2, kb2, vtb, ctxb);

    gemm_nt_f32<<<dim3(16, 32), 256, 0, stream>>>(ctxb, wob, out, M, D, D);
}